// Round 19
// baseline (145.906 us; speedup 1.0000x reference)
//
#include <hip/hip_runtime.h>
#include <math.h>

// n=16384 Gaussian points in 3D. Exact 12-NN (incl self) per point:
//   out[i] = b + ( (W·p_i)·(1 + 11/sqrt(2)) + 0.5 * sum_{11NN} W·|p_i - p_j| ) / 12
//
// R19: sort unchanged (R16 best-measured: memset -> fused 64-block sort with
// 2 gbars). Query: TWO independent queries per wave, source-interleaved for
// ILP/MLP (query kernel was 49% VALUBusy = latency-bound with one serial
// load stream; pairing overlaps A's load latency with B's VALU). 8192 waves,
// 2048 blocks x 256. Per query, logic identical to the 5x-verified path:
// best axis by max |coord| -> seed 768 -> u = 12th of 64 lane minima ->
// extent from prefix sums -> 4-deep paired collect -> count-down extraction
// (remove r=C-12 largest; r>8 -> 12-round select) -> reduce, write.
// Overflow (rare, wave-uniform) -> exact med3 fallback over the extent.

#define NBINS  2048
#define CMIN_  (-6.0f)
#define INVBW_ ((float)NBINS / 12.0f)
#define SORTB  64
#define BLOCK  256
#define SEED   768
#define KK     12
#define CD     4
#define BIG    3.0e38f

__device__ __forceinline__ int bin_of(float x) {
  int b = (int)((x - CMIN_) * INVBW_);
  b = b < 0 ? 0 : b;
  b = b > NBINS - 1 ? NBINS - 1 : b;
  return b;
}

__device__ __forceinline__ void gbar(int* c, int target) {
  __syncthreads();
  if (threadIdx.x == 0) {
    __threadfence();
    atomicAdd(c, 1);
    while (atomicAdd(c, 0) < target) __builtin_amdgcn_s_sleep(2);
    __threadfence();
  }
  __syncthreads();
}

__device__ __forceinline__ float wave_min(float v) {
#pragma unroll
  for (int o = 1; o < 64; o <<= 1) v = fminf(v, __shfl_xor(v, o));
  return v;
}

__device__ __forceinline__ float wave_max(float v) {
#pragma unroll
  for (int o = 1; o < 64; o <<= 1) v = fmaxf(v, __shfl_xor(v, o));
  return v;
}

// sorted ascending 4-deep paired insert (static indexing -> registers)
__device__ __forceinline__ void ins4(float (&qd)[CD], float (&qw)[CD],
                                     float d, float w) {
#pragma unroll
  for (int k = CD - 1; k >= 1; --k) {
    const bool up  = (qd[k - 1] > d);
    const bool mid = (qd[k] > d);
    const float nd = up ? qd[k - 1] : (mid ? d : qd[k]);
    const float nw = up ? qw[k - 1] : (mid ? w : qw[k]);
    qd[k] = nd; qw[k] = nw;
  }
  if (qd[0] > d) { qw[0] = w; qd[0] = d; }
}

// count-down / select extraction over collected entries (wave-uniform path)
__device__ __forceinline__ float extract12(float (&qd)[CD], float (&qw)[CD],
                                           int ccnt, int lane) {
  float acc = 0.f;
  int C = ccnt;
#pragma unroll
  for (int o = 1; o < 64; o <<= 1) C += __shfl_xor(C, o);
  acc = qw[0] + qw[1] + qw[2] + qw[3];
  const int r = C - KK;
  if (r <= 8) {
    for (int it = 0; it < r; ++it) {
      const bool v3 = qd[3] < BIG, v2 = qd[2] < BIG;
      const bool v1 = qd[1] < BIG, v0 = qd[0] < BIG;
      const float mx = v3 ? qd[3] : (v2 ? qd[2] : (v1 ? qd[1] : (v0 ? qd[0] : -1.f)));
      const float wm = wave_max(mx);
      const bool hit = (mx == wm) && (mx >= 0.f);
      const unsigned long long bal = __ballot(hit);
      if (hit && lane == (int)(__ffsll(bal) - 1)) {
        if (v3)      { acc -= qw[3]; qd[3] = BIG; qw[3] = 0.f; }
        else if (v2) { acc -= qw[2]; qd[2] = BIG; qw[2] = 0.f; }
        else if (v1) { acc -= qw[1]; qd[1] = BIG; qw[1] = 0.f; }
        else         { acc -= qw[0]; qd[0] = BIG; qw[0] = 0.f; }
      }
    }
  } else {
    acc = 0.f;
#pragma unroll
    for (int rr = 0; rr < KK; ++rr) {
      const float mm = wave_min(qd[0]);
      const unsigned long long bal = __ballot(qd[0] == mm);
      if (qd[0] == mm && lane == (int)(__ffsll(bal) - 1)) {
        acc += qw[0];
#pragma unroll
        for (int k = 0; k < CD - 1; ++k) { qd[k] = qd[k + 1]; qw[k] = qw[k + 1]; }
        qd[CD - 1] = BIG;
      }
    }
  }
  return acc;
}

// exact med3 fallback over [lo2,hi2): top-12 -> tau -> masked rescan
__device__ __forceinline__ float fallback12(const float4* __restrict__ sv,
                                            int lo2, int hi2, int steps,
                                            float xi, float yi, float zi,
                                            float W0, float W1, float W2,
                                            int lane) {
  float dd[KK];
#pragma unroll
  for (int k = 0; k < KK; ++k) dd[k] = BIG;
  for (int s0 = 0; s0 < steps; ++s0) {
    const int pos = lo2 + s0 * 64 + lane;
    const float4 c = sv[(pos < hi2) ? pos : hi2 - 1];
    const float dx = xi - c.x, dy = yi - c.y, dz = zi - c.z;
    const float d2 = (pos < hi2) ? fmaf(dx, dx, fmaf(dy, dy, dz * dz)) : BIG;
#pragma unroll
    for (int k = KK - 1; k >= 1; --k)
      dd[k] = __builtin_amdgcn_fmed3f(d2, dd[k - 1], dd[k]);
    dd[0] = fminf(dd[0], d2);
  }
  float tau = 0.f;
#pragma unroll
  for (int r = 0; r < KK; ++r) {
    const float mm = wave_min(dd[0]);
    if (dd[0] == mm) {
#pragma unroll
      for (int k = 0; k < KK - 1; ++k) dd[k] = dd[k + 1];
      dd[KK - 1] = BIG;
    }
    tau = mm;
  }
  float acc = 0.f;
  for (int s0 = 0; s0 < steps; ++s0) {
    const int pos = lo2 + s0 * 64 + lane;
    if (pos < hi2) {
      const float4 c = sv[pos];
      const float dx = xi - c.x, dy = yi - c.y, dz = zi - c.z;
      const float d2 = fmaf(dx, dx, fmaf(dy, dy, dz * dz));
      const float w  = fmaf(W0, fabsf(dx), fmaf(W1, fabsf(dy), W2 * fabsf(dz)));
      acc += (d2 <= tau) ? w : 0.f;
    }
  }
  return acc;
}

// ---------------- K1: fused 3-axis sort (64 blocks, 2 gbar barriers) ---------
__global__ __launch_bounds__(256)
void sort64_kernel(const float* __restrict__ p, int* __restrict__ hist,
                   int* __restrict__ cursorEnd, int* __restrict__ scatCur,
                   int* __restrict__ cnt, float4* __restrict__ s_all, int n) {
  __shared__ int ssum[256];
  const int tid = threadIdx.x;
  const int gid = blockIdx.x * 256 + tid;

  float x, y, z;
  if (gid < n) {
    x = p[3 * gid]; y = p[3 * gid + 1]; z = p[3 * gid + 2];
    atomicAdd(&hist[bin_of(x)], 1);
    atomicAdd(&hist[NBINS + bin_of(y)], 1);
    atomicAdd(&hist[2 * NBINS + bin_of(z)], 1);
  }
  gbar(&cnt[0], SORTB);

  if (blockIdx.x < 3) {
    const int dim = blockIdx.x;
    const int* __restrict__ h = hist + dim * NBINS;
    int* __restrict__ ce = cursorEnd + dim * NBINS;
    int* __restrict__ sc = scatCur + dim * NBINS;
    const int base = tid * (NBINS / 256);
    int v[NBINS / 256];
    int sum = 0;
#pragma unroll
    for (int t = 0; t < NBINS / 256; ++t) { v[t] = h[base + t]; sum += v[t]; }
    ssum[tid] = sum;
    __syncthreads();
    for (int off = 1; off < 256; off <<= 1) {
      const int a = (tid >= off) ? ssum[tid - off] : 0;
      __syncthreads();
      ssum[tid] += a;
      __syncthreads();
    }
    int run = (tid > 0) ? ssum[tid - 1] : 0;
#pragma unroll
    for (int t = 0; t < NBINS / 256; ++t) {
      sc[base + t] = run;
      run += v[t];
      ce[base + t] = run;
    }
  }
  gbar(&cnt[1], SORTB);

  if (gid < n) {
    const float4 v = make_float4(x, y, z, __int_as_float(gid));
    const int px = atomicAdd(&scatCur[bin_of(x)], 1);
    const int py = atomicAdd(&scatCur[NBINS + bin_of(y)], 1);
    const int pz = atomicAdd(&scatCur[2 * NBINS + bin_of(z)], 1);
    s_all[px] = v;
    s_all[n + py] = v;
    s_all[2 * n + pz] = v;
  }
}

// ---------------- K2: query (TWO queries per wave, interleaved) --------------
__global__ __launch_bounds__(BLOCK)
void query_kernel(const float4* __restrict__ sx, const float4* __restrict__ sy,
                  const float4* __restrict__ sz, const int* __restrict__ cx,
                  const int* __restrict__ cy, const int* __restrict__ cz,
                  const float* __restrict__ W, const float* __restrict__ bias,
                  float* __restrict__ out, int n) {
  const int lane = threadIdx.x & 63;
  const int wv   = threadIdx.x >> 6;
  const int g    = wv * (n >> 3) + blockIdx.x;     // octant interleave, 0..8191
  const int t0   = 2 * g;
  const int t1   = 2 * g + 1;
  const float W0 = W[0], W1 = W[1], W2 = W[2];
  const float bb = bias[0];

  const float4 me0 = sx[t0];
  const float4 me1 = sx[t1];
  const float xi0 = me0.x, yi0 = me0.y, zi0 = me0.z;
  const float xi1 = me1.x, yi1 = me1.y, zi1 = me1.z;
  const int orig0 = __float_as_int(me0.w);
  const int orig1 = __float_as_int(me1.w);

  // ---- axis choice (wave-uniform, per query) ----
  const float ax0 = fabsf(xi0), ay0 = fabsf(yi0), az0 = fabsf(zi0);
  const float4* sv0; const int* cur0; float cq0;
  if (ay0 >= ax0 && ay0 >= az0)      { sv0 = sy; cur0 = cy; cq0 = yi0; }
  else if (az0 >= ax0 && az0 >= ay0) { sv0 = sz; cur0 = cz; cq0 = zi0; }
  else                               { sv0 = sx; cur0 = cx; cq0 = xi0; }
  const float ax1 = fabsf(xi1), ay1 = fabsf(yi1), az1 = fabsf(zi1);
  const float4* sv1; const int* cur1; float cq1;
  if (ay1 >= ax1 && ay1 >= az1)      { sv1 = sy; cur1 = cy; cq1 = yi1; }
  else if (az1 >= ax1 && az1 >= ay1) { sv1 = sz; cur1 = cz; cq1 = zi1; }
  else                               { sv1 = sx; cur1 = cx; cq1 = xi1; }

  // ---- seed windows ----
  const int bq0 = bin_of(cq0);
  const int bq1 = bin_of(cq1);
  int lo0 = (((bq0 > 0 ? cur0[bq0 - 1] : 0) + cur0[bq0]) >> 1) - SEED / 2;
  int lo1 = (((bq1 > 0 ? cur1[bq1 - 1] : 0) + cur1[bq1]) >> 1) - SEED / 2;
  lo0 = lo0 < 0 ? 0 : (lo0 > n - SEED ? n - SEED : lo0);
  lo1 = lo1 < 0 ? 0 : (lo1 > n - SEED ? n - SEED : lo1);
  const float4* base0 = sv0 + lo0 + lane;
  const float4* base1 = sv1 + lo1 + lane;

  // ---- 1. seed lane-minima, interleaved (2 loads in flight / iter) ----
  float m0 = BIG, m1 = BIG;
#pragma unroll
  for (int s = 0; s < SEED / 64; ++s) {
    const float4 c0 = base0[s * 64];
    const float4 c1 = base1[s * 64];
    {
      const float dx = xi0 - c0.x, dy = yi0 - c0.y, dz = zi0 - c0.z;
      m0 = fminf(m0, fmaf(dx, dx, fmaf(dy, dy, dz * dz)));
    }
    {
      const float dx = xi1 - c1.x, dy = yi1 - c1.y, dz = zi1 - c1.z;
      m1 = fminf(m1, fmaf(dx, dx, fmaf(dy, dy, dz * dz)));
    }
  }

  // ---- 2. u = 12th smallest of 64 lane minima, both interleaved ----
  float u0, u1;
  {
    float v0 = m0, v1 = m1;
#pragma unroll
    for (int r = 0; r < KK; ++r) {
      const float mm0 = wave_min(v0);
      const float mm1 = wave_min(v1);
      u0 = mm0; u1 = mm1;
      v0 = (v0 == mm0) ? BIG : v0;
      v1 = (v1 == mm1) ? BIG : v1;
    }
  }

  // ---- 3. extents ----
  const float s0r = sqrtf(u0), s1r = sqrtf(u1);
  const int bl0 = bin_of(cq0 - s0r), bh0 = bin_of(cq0 + s0r);
  const int bl1 = bin_of(cq1 - s1r), bh1 = bin_of(cq1 + s1r);
  const int lo20 = (bl0 > 0) ? cur0[bl0 - 1] : 0;
  const int hi20 = cur0[bh0];
  const int lo21 = (bl1 > 0) ? cur1[bl1 - 1] : 0;
  const int hi21 = cur1[bh1];
  const int steps0 = (hi20 - lo20 + 63) >> 6;
  const int steps1 = (hi21 - lo21 + 63) >> 6;
  const int msteps = steps0 > steps1 ? steps0 : steps1;

  // ---- fused collect loop (guards wave-uniform; 2 loads in flight) ----
  float qd0[CD], qw0[CD], qd1[CD], qw1[CD];
  int ccnt0 = 0, ccnt1 = 0;
#pragma unroll
  for (int k = 0; k < CD; ++k) { qd0[k] = BIG; qw0[k] = 0.f; qd1[k] = BIG; qw1[k] = 0.f; }

  for (int st = 0; st < msteps; ++st) {
    if (st < steps0) {
      const int pos = lo20 + st * 64 + lane;
      const float4 c = sv0[(pos < hi20) ? pos : hi20 - 1];
      const float dx = xi0 - c.x, dy = yi0 - c.y, dz = zi0 - c.z;
      const float d2 = (pos < hi20) ? fmaf(dx, dx, fmaf(dy, dy, dz * dz)) : BIG;
      if (d2 <= u0) {
        const float w = fmaf(W0, fabsf(dx), fmaf(W1, fabsf(dy), W2 * fabsf(dz)));
        ++ccnt0; ins4(qd0, qw0, d2, w);
      }
    }
    if (st < steps1) {
      const int pos = lo21 + st * 64 + lane;
      const float4 c = sv1[(pos < hi21) ? pos : hi21 - 1];
      const float dx = xi1 - c.x, dy = yi1 - c.y, dz = zi1 - c.z;
      const float d2 = (pos < hi21) ? fmaf(dx, dx, fmaf(dy, dy, dz * dz)) : BIG;
      if (d2 <= u1) {
        const float w = fmaf(W0, fabsf(dx), fmaf(W1, fabsf(dy), W2 * fabsf(dz)));
        ++ccnt1; ins4(qd1, qw1, d2, w);
      }
    }
  }

  // ---- 4. extraction (wave-uniform branches, per query) ----
  float acc0, acc1;
  const bool ovf0 = __ballot(ccnt0 > CD) != 0ULL;
  const bool ovf1 = __ballot(ccnt1 > CD) != 0ULL;
  if (!ovf0) acc0 = extract12(qd0, qw0, ccnt0, lane);
  else       acc0 = fallback12(sv0, lo20, hi20, steps0, xi0, yi0, zi0, W0, W1, W2, lane);
  if (!ovf1) acc1 = extract12(qd1, qw1, ccnt1, lane);
  else       acc1 = fallback12(sv1, lo21, hi21, steps1, xi1, yi1, zi1, W0, W1, W2, lane);

  // ---- 5. reduce + write (interleaved shfl chains) ----
#pragma unroll
  for (int o = 1; o < 64; o <<= 1) {
    acc0 += __shfl_xor(acc0, o);
    acc1 += __shfl_xor(acc1, o);
  }
  if (lane == 0) {
    const float xw00 = W0 * xi0 + W1 * yi0 + W2 * zi0;
    const float xw01 = W0 * xi1 + W1 * yi1 + W2 * zi1;
    // 1 + 11/sqrt(2)
    out[orig0] = bb + (xw00 * 8.778174593052022f + 0.5f * acc0) * (1.0f / 12.0f);
    out[orig1] = bb + (xw01 * 8.778174593052022f + 0.5f * acc1) * (1.0f / 12.0f);
  }
}

extern "C" void kernel_launch(void* const* d_in, const int* in_sizes, int n_in,
                              void* d_out, int out_size, void* d_ws, size_t ws_size,
                              hipStream_t stream) {
  const float* p  = (const float*)d_in[0];
  const float* W  = (const float*)d_in[1];
  const float* bb = (const float*)d_in[2];
  float* out = (float*)d_out;

  const int n = in_sizes[0] / 3;   // 16384

  // ws: hist 3x2048 @0 | cnt[16] @24576 | cursorEnd 3x2048 @24640
  //     | scatCur 3x2048 @49216 | sorted 3xn float4 @73792
  int*    hist      = (int*)d_ws;
  int*    cnt       = (int*)((char*)d_ws + 24576);
  int*    cursorEnd = (int*)((char*)d_ws + 24640);
  int*    scatCur   = (int*)((char*)d_ws + 49216);
  float4* s_all     = (float4*)((char*)d_ws + 73792);

  int*    cx = cursorEnd;
  int*    cy = cx + NBINS;
  int*    cz = cy + NBINS;
  float4* sx = s_all;
  float4* sy = sx + n;
  float4* sz = sy + n;

  hipMemsetAsync(d_ws, 0, 24640, stream);   // hist + cnt
  sort64_kernel<<<SORTB, 256, 0, stream>>>(p, hist, cursorEnd, scatCur, cnt, s_all, n);
  query_kernel<<<n / 8, BLOCK, 0, stream>>>(sx, sy, sz, cx, cy, cz, W, bb, out, n);
}